// Round 3
// baseline (145.210 us; speedup 1.0000x reference)
//
#include <hip/hip_runtime.h>

using f32x4  = __attribute__((ext_vector_type(4))) float;
using bf16x8 = __attribute__((ext_vector_type(8))) short;

#define DEV static __device__ __forceinline__

DEV unsigned short f2bf(float f){
  unsigned u = __float_as_uint(f);
  unsigned r = (u + 0x7FFFu + ((u >> 16) & 1u)) >> 16;
  return (unsigned short)r;
}

// vTp storage permutation: within each 64-n chunk, n=[h2|t|g1 g0|u1 u0] -> p=[h2|g1 g0|t|u1 u0]
DEV int vperm(int n){
  return (n & ~63) | (n & 32) | ((n & 0xC) << 1) | ((n & 0x10) >> 2) | (n & 3);
}

// ---------------- K0: weight prep ------------------------------------------
__global__ __launch_bounds__(256) void prep_kernel(
    const float* __restrict__ fp_w, const float* __restrict__ q_w,
    const float* __restrict__ k_w, const float* __restrict__ v_w,
    const float* __restrict__ o_w, const float* __restrict__ s0_w,
    const float* __restrict__ s1_w, const float* __restrict__ fu_w,
    const float* __restrict__ pr1_w, const float* __restrict__ pr2_w,
    const float* __restrict__ rg_w,
    unsigned short* __restrict__ fpw_bf, unsigned short* __restrict__ wcat_bf,
    float* __restrict__ o_wT, float* __restrict__ fu_wT, float* __restrict__ pr1_wT,
    float* __restrict__ s0_wT, float* __restrict__ s1_wT0, float* __restrict__ s1_wT1,
    float* __restrict__ pr2_wT, float* __restrict__ rg_wT){
  int i = blockIdx.x * 256 + threadIdx.x;
  const int stride = 128 * 256;
  for (int idx = i; idx < 128 * 2048; idx += stride) fpw_bf[idx] = f2bf(fp_w[idx]);
  for (int idx = i; idx < 384 * 128; idx += stride){
    int c = idx >> 7, k = idx & 127;
    float v;
    if (c < 128)      v = q_w[c * 128 + k] * 0.25f;   // fold 1/sqrt(hd)
    else if (c < 256) v = k_w[(c - 128) * 128 + k];
    else              v = v_w[(c - 256) * 128 + k];
    wcat_bf[idx] = f2bf(v);
  }
  for (int idx = i; idx < 128 * 128; idx += stride){
    int k = idx >> 7, c = idx & 127;
    o_wT[idx]   = o_w[c * 128 + k];
    fu_wT[idx]  = fu_w[c * 128 + k];
    pr1_wT[idx] = pr1_w[c * 128 + k];
    s0_wT[idx]  = s0_w[c * 128 + k];             // (o,i,1)
    s1_wT0[idx] = s1_w[(c * 128 + k) * 2 + 0];   // (o,i,2)
    s1_wT1[idx] = s1_w[(c * 128 + k) * 2 + 1];
  }
  for (int idx = i; idx < 128 * 24; idx += stride){
    int k = idx / 24, c = idx % 24;
    pr2_wT[idx] = pr2_w[c * 128 + k];
    rg_wT[idx]  = rg_w[c * 128 + k];
  }
}

// ---------------- K1: conv + feat GEMM + LN + qkv, fully fused -------------
__global__ __launch_bounds__(512) void fused_feat_kernel(
    const float* __restrict__ x, const float* __restrict__ tc_w,
    const float* __restrict__ tc_b, const float* __restrict__ bn_g,
    const float* __restrict__ bn_b,
    const unsigned short* __restrict__ fpw, const float* __restrict__ fp_b,
    const float* __restrict__ ln_g, const float* __restrict__ ln_b,
    const unsigned short* __restrict__ wcat, const float* __restrict__ q_b,
    const float* __restrict__ k_b, const float* __restrict__ v_b,
    unsigned short* __restrict__ qo, unsigned short* __restrict__ ko,
    unsigned short* __restrict__ vTp){
  __shared__ float xs[64][17];
  __shared__ unsigned short fs[16 * 1024];   // one K-half, XOR-swizzled (32 KB)
  __shared__ float pre[16][128];
  __shared__ unsigned short ft[16 * 128];    // feats bf16, XOR-swizzled
  __shared__ float stat[16][2];
  int t = threadIdx.x;
  int lane = t & 63, w = t >> 6, l15 = lane & 15, g = lane >> 4;
  int row0 = blockIdx.x * 16;
  int b = row0 >> 11, n0 = row0 & 2047;
  for (int e = t; e < 1024; e += 512){
    int tt = e >> 4, nn2 = e & 15;
    xs[tt][nn2] = x[(size_t)(b * 64 + tt) * 2048 + n0 + nn2];
  }
  // per-thread conv channel setup: thread -> (nn = t&15, ch = t>>4)
  int nn = t & 15, ch = t >> 4;              // ch 0..31
  float cw0 = tc_w[ch * 3 + 0], cw1 = tc_w[ch * 3 + 1], cw2 = tc_w[ch * 3 + 2];
  float cbias = tc_b[ch];
  float cbnsc = rsqrtf(1.0f + 1e-5f) * bn_g[ch];
  float cbnb  = bn_b[ch];
  int toff = (ch & 3) << 4;                  // rotate t per channel: spreads LDS banks
  f32x4 acc = {0.f, 0.f, 0.f, 0.f};
  const unsigned short* bp = fpw + (size_t)(w * 16 + l15) * 2048 + g * 8;
  __syncthreads();
  for (int half = 0; half < 2; half++){
    if ((ch >> 4) == half){
      int cl = ch & 15;
      #pragma unroll
      for (int i = 0; i < 64; i++){
        int tt = (i + toff) & 63;
        float xm = (tt > 0)  ? xs[tt - 1][nn] : 0.f;
        float xv = xs[tt][nn];
        float xp = (tt < 63) ? xs[tt + 1][nn] : 0.f;
        float y = (xm * cw0 + xv * cw1 + xp * cw2 + cbias) * cbnsc + cbnb;
        int kl = cl * 64 + tt;
        int byte = nn * 2048 + ((kl * 2) ^ ((nn & 7) << 4));
        *(unsigned short*)((char*)fs + byte) = f2bf(fmaxf(y, 0.f));
      }
    }
    __syncthreads();
    #pragma unroll 4
    for (int kk = 0; kk < 1024; kk += 32){
      int abyte = l15 * 2048 + (((kk + g * 8) * 2) ^ ((l15 & 7) << 4));
      bf16x8 a  = *(const bf16x8*)((const char*)fs + abyte);
      bf16x8 bb = *(const bf16x8*)(bp + half * 1024 + kk);
      acc = __builtin_amdgcn_mfma_f32_16x16x32_bf16(a, bb, acc, 0, 0, 0);
    }
    __syncthreads();   // fs about to be overwritten by next half
  }
  {
    int c0 = w * 16;
    #pragma unroll
    for (int r = 0; r < 4; r++)
      pre[g * 4 + r][c0 + l15] = acc[r] + fp_b[c0 + l15];
  }
  __syncthreads();
  if (t < 256){
    int r = t >> 4, j = t & 15;
    float s = 0.f, ss = 0.f;
    #pragma unroll
    for (int q = 0; q < 8; q++){ float v = pre[r][j + q * 16]; s += v; ss += v * v; }
    #pragma unroll
    for (int m = 1; m < 16; m <<= 1){ s += __shfl_xor(s, m, 64); ss += __shfl_xor(ss, m, 64); }
    if (j == 0){
      float mean = s * (1.f / 128.f);
      stat[r][0] = mean;
      stat[r][1] = rsqrtf(ss * (1.f / 128.f) - mean * mean + 1e-5f);
    }
  }
  __syncthreads();
  if (t < 256){
    int r = t >> 4, j = t & 15;
    float mean = stat[r][0], rstd = stat[r][1];
    bf16x8 outv;
    #pragma unroll
    for (int q = 0; q < 8; q++){
      int cc = j * 8 + q;
      float v = (pre[r][cc] - mean) * rstd * ln_g[cc] + ln_b[cc];
      outv[q] = (short)f2bf(fmaxf(v, 0.f));
    }
    int byte = r * 256 + ((j * 16) ^ ((r & 7) << 4));
    *(bf16x8*)((char*)ft + byte) = outv;
  }
  __syncthreads();
  // qkv: 8 waves x 3 col-tiles of 16 = 384 output channels
  f32x4 acc3[3] = {{0,0,0,0},{0,0,0,0},{0,0,0,0}};
  #pragma unroll
  for (int kk = 0; kk < 128; kk += 32){
    int abyte = l15 * 256 + (((kk + g * 8) * 2) ^ ((l15 & 7) << 4));
    bf16x8 a = *(const bf16x8*)((const char*)ft + abyte);
    #pragma unroll
    for (int ci = 0; ci < 3; ci++){
      int c0 = w * 48 + ci * 16;
      bf16x8 bb = *(const bf16x8*)(wcat + (size_t)(c0 + l15) * 128 + g * 8 + kk);
      acc3[ci] = __builtin_amdgcn_mfma_f32_16x16x32_bf16(a, bb, acc3[ci], 0, 0, 0);
    }
  }
  #pragma unroll
  for (int ci = 0; ci < 3; ci++){
    int c = w * 48 + ci * 16 + l15;
    int mat = c >> 7, cm = c & 127;
    int hh = cm >> 4, d = cm & 15;
    float bias = (mat == 0) ? q_b[cm] * 0.25f : (mat == 1 ? k_b[cm] : v_b[cm]);
    int bh = b * 8 + hh;
    #pragma unroll
    for (int r = 0; r < 4; r++){
      int n = n0 + g * 4 + r;
      unsigned short bv = f2bf(acc3[ci][r] + bias);
      if (mat == 0)      qo[((size_t)bh * 2048 + n) * 16 + d] = bv;
      else if (mat == 1) ko[((size_t)bh * 2048 + n) * 16 + d] = bv;
      else               vTp[((size_t)bh * 16 + d) * 2048 + vperm(n)] = bv;
    }
  }
}

// ---------------- K2: attention, swapped-operand, zero-LDS main loop -------
__global__ __launch_bounds__(256) void attn_kernel(
    const unsigned short* __restrict__ qo, const unsigned short* __restrict__ ko,
    const unsigned short* __restrict__ vTp, const float* __restrict__ adj,
    float* __restrict__ go){
  __shared__ float red_acc[4][2][16][16];   // [w][b][d][q]
  __shared__ float red_rs[4][2][16];        // [w][b][q]
  int t = threadIdx.x, lane = t & 63, w = t >> 6;
  int l15 = lane & 15, g = lane >> 4;
  int h = blockIdx.x >> 7;                  // 0..7
  int row0 = (blockIdx.x & 127) * 16;       // 16 q-rows
  const bf16x8 zf = {0,0,0,0,0,0,0,0};
  const f32x4 z4 = {0.f,0.f,0.f,0.f};
  // B-operand Q fragment: lane col = q-row (l15), k = d (g*8..), pad g>=2
  bf16x8 qf[2];
  #pragma unroll
  for (int b = 0; b < 2; b++){
    if (g < 2) qf[b] = *(const bf16x8*)(qo + ((size_t)(b * 8 + h) * 2048 + row0 + l15) * 16 + g * 8);
    else       qf[b] = zf;
  }
  f32x4 accv[2] = {{0.f,0.f,0.f,0.f},{0.f,0.f,0.f,0.f}};
  float rsp[2] = {0.f, 0.f};
  const float* adjrow = adj + ((size_t)h * 2048 + row0 + l15) * 2048 + g * 4;
  const int mbeg = w * 512;
  for (int m0 = mbeg; m0 < mbeg + 512; m0 += 64){
    f32x4 adjv[4];
    #pragma unroll
    for (int s = 0; s < 4; s++)
      adjv[s] = *(const f32x4*)(adjrow + m0 + s * 16);   // adj^T frag: vector load
    #pragma unroll
    for (int b = 0; b < 2; b++){
      int bh = b * 8 + h;
      const unsigned short* kbase = ko + (size_t)bh * 2048 * 16;
      f32x4 sf[4];
      #pragma unroll
      for (int s = 0; s < 4; s++){
        bf16x8 kf;   // A-operand: lane row = K-row m (l15), k = d
        if (g < 2) kf = *(const bf16x8*)(kbase + (size_t)(m0 + s * 16 + l15) * 16 + g * 8);
        else       kf = zf;
        sf[s] = __builtin_amdgcn_mfma_f32_16x16x32_bf16(kf, qf[b], z4, 0, 0, 0);
      }
      // S^T: lane (g,l15) holds S[m = m0+s*16+g*4+r][q = l15]
      bf16x8 pf[2];
      float partial = 0.f;
      #pragma unroll
      for (int s = 0; s < 4; s++){
        #pragma unroll
        for (int r = 0; r < 4; r++){
          float p = __expf(sf[s][r] + adjv[s][r]);   // tiny scores: no-max softmax
          partial += p;
          pf[s >> 1][(s & 1) * 4 + r] = (short)f2bf(p);
        }
      }
      rsp[b] += partial;
      // PV: A = V^T (perm-stored, contiguous), B = lane-local packed P
      const unsigned short* vbase = vTp + ((size_t)bh * 16 + l15) * 2048 + m0;
      #pragma unroll
      for (int h2 = 0; h2 < 2; h2++){
        bf16x8 vf = *(const bf16x8*)(vbase + h2 * 32 + g * 8);
        accv[b] = __builtin_amdgcn_mfma_f32_16x16x32_bf16(vf, pf[h2], accv[b], 0, 0, 0);
      }
    }
  }
  // reduce across g-groups (denominator) and across waves
  #pragma unroll
  for (int b = 0; b < 2; b++){
    float s = rsp[b];
    s += __shfl_xor(s, 16, 64);
    s += __shfl_xor(s, 32, 64);
    #pragma unroll
    for (int r = 0; r < 4; r++) red_acc[w][b][g * 4 + r][l15] = accv[b][r];
    if (lane < 16) red_rs[w][b][l15] = s;
  }
  __syncthreads();
  for (int i = t; i < 512; i += 256){
    int b = i >> 8, q = (i >> 4) & 15, d = i & 15;
    float v = 0.f, den = 0.f;
    #pragma unroll
    for (int ww = 0; ww < 4; ww++){ v += red_acc[ww][b][d][q]; den += red_rs[ww][b][q]; }
    go[((size_t)b * 2048 + row0 + q) * 128 + h * 16 + d] = v / den;
  }
}

// ---------------- K3: o-proj + s0/s1 convs + interp + fusion + tail --------
__global__ __launch_bounds__(1024) void tail_kernel(
    const float* __restrict__ go, const float* __restrict__ x,
    const float* __restrict__ o_wT, const float* __restrict__ o_b,
    const float* __restrict__ s0_wT, const float* __restrict__ s0_b,
    const float* __restrict__ s0_g, const float* __restrict__ s0_bb,
    const float* __restrict__ s1_wT0, const float* __restrict__ s1_wT1,
    const float* __restrict__ s1_b, const float* __restrict__ s1_g,
    const float* __restrict__ s1_bb, const float* __restrict__ fw,
    const float* __restrict__ fu_wT, const float* __restrict__ fu_b,
    const float* __restrict__ fu_g, const float* __restrict__ fu_bb,
    const float* __restrict__ pr1_wT, const float* __restrict__ pr1_b,
    const float* __restrict__ pr_g, const float* __restrict__ pr_bb,
    const float* __restrict__ pr2_wT, const float* __restrict__ pr2_b,
    const float* __restrict__ rg_wT, const float* __restrict__ rg_b,
    float* __restrict__ out){
  __shared__ float go_s[18][128];
  __shared__ float gf_s[18][128];
  __shared__ float f1_s[17][128];
  __shared__ float fu_in[16][128];
  __shared__ float pre_s[16][128];
  __shared__ float ff_s[16][128];
  __shared__ float h_s[16][128];
  __shared__ float stat[16][2];
  int t = threadIdx.x;
  int b = blockIdx.x >> 7;
  int n0 = (blockIdx.x & 127) * 16;
  for (int e = t; e < 18 * 128; e += 1024){
    int lr = e >> 7, cc = e & 127;
    int gn = n0 - 1 + lr;
    go_s[lr][cc] = (gn >= 0 && gn < 2048) ? go[((size_t)b * 2048 + gn) * 128 + cc] : 0.f;
  }
  __syncthreads();
  int c = t & 127, q8 = t >> 7;   // q8 = 0..7; rows q8, q8+8, (q8+16 if <18)
  const float bninv = rsqrtf(1.0f + 1e-5f);
  { // gf = go @ o_w^T + o_b (18 rows incl halo; zero outside [0,2048))
    float bias = o_b[c];
    float a0 = bias, a1 = bias, a2 = bias;
    for (int k = 0; k < 128; k++){
      float wv = o_wT[k * 128 + c];
      a0 += go_s[q8][k] * wv;
      a1 += go_s[q8 + 8][k] * wv;
      if (q8 < 2) a2 += go_s[q8 + 16][k] * wv;
    }
    int gn = n0 - 1 + q8;
    gf_s[q8][c]      = (gn >= 0 && gn < 2048) ? a0 : 0.f;
    gf_s[q8 + 8][c]  = (gn + 8 < 2048) ? a1 : 0.f;
    if (q8 < 2) gf_s[q8 + 16][c] = (gn + 16 < 2048) ? a2 : 0.f;
  }
  __syncthreads();
  { // f1[lr] = relu(bn1(gf[lr]@w0 + gf[lr+1]@w1)), rows 0..16
    float bias = s1_b[c];
    float a0 = bias, a1 = bias, a2 = bias;
    for (int k = 0; k < 128; k++){
      float w0 = s1_wT0[k * 128 + c], w1 = s1_wT1[k * 128 + c];
      a0 += gf_s[q8][k] * w0 + gf_s[q8 + 1][k] * w1;
      a1 += gf_s[q8 + 8][k] * w0 + gf_s[q8 + 9][k] * w1;
      if (q8 == 0) a2 += gf_s[16][k] * w0 + gf_s[17][k] * w1;
    }
    float sc = s1_g[c] * bninv, bb2 = s1_bb[c];
    f1_s[q8][c]     = fmaxf(a0 * sc + bb2, 0.f);
    f1_s[q8 + 8][c] = fmaxf(a1 * sc + bb2, 0.f);
    if (q8 == 0) f1_s[16][c] = fmaxf(a2 * sc + bb2, 0.f);
  }
  __syncthreads();
  { // fused = a0*f0 + a1*interp(f1), rows 0..15
    float bias = s0_b[c];
    float a0 = bias, a1 = bias;
    for (int k = 0; k < 128; k++){
      float wv = s0_wT[k * 128 + c];
      a0 += gf_s[q8 + 1][k] * wv;
      a1 += gf_s[q8 + 9][k] * wv;
    }
    float e0 = __expf(fw[0]), e1 = __expf(fw[1]);
    float al0 = e0 / (e0 + e1), al1 = e1 / (e0 + e1);
    float sc = s0_g[c] * bninv, bb2 = s0_bb[c];
    #pragma unroll
    for (int i = 0; i < 2; i++){
      int lr = q8 + i * 8;
      float accv = i ? a1 : a0;
      int n = n0 + lr;
      float f0 = fmaxf(accv * sc + bb2, 0.f);
      float wn = (n + 0.5f) * (1.0f / 2048.0f);
      fu_in[lr][c] = al0 * f0 + al1 * ((1.f - wn) * f1_s[lr][c] + wn * f1_s[lr + 1][c]);
    }
  }
  __syncthreads();
  { // fu linear
    float bias = fu_b[c];
    float a0 = bias, a1 = bias;
    for (int k = 0; k < 128; k++){
      float wv = fu_wT[k * 128 + c];
      a0 += fu_in[q8][k] * wv;
      a1 += fu_in[q8 + 8][k] * wv;
    }
    pre_s[q8][c] = a0;
    pre_s[q8 + 8][c] = a1;
  }
  __syncthreads();
  if (t < 256){ // LN stats
    int r = t >> 4, j = t & 15;
    float s = 0.f, ss = 0.f;
    #pragma unroll
    for (int q = 0; q < 8; q++){ float v = pre_s[r][j + q * 16]; s += v; ss += v * v; }
    #pragma unroll
    for (int m = 1; m < 16; m <<= 1){ s += __shfl_xor(s, m, 64); ss += __shfl_xor(ss, m, 64); }
    if (j == 0){ float mean = s * (1.f / 128.f); stat[r][0] = mean;
                 stat[r][1] = rsqrtf(ss * (1.f / 128.f) - mean * mean + 1e-5f); }
  }
  __syncthreads();
  if (t < 256){
    int r = t >> 4, j = t & 15;
    float mean = stat[r][0], rstd = stat[r][1];
    #pragma unroll
    for (int q = 0; q < 8; q++){
      int cc = j * 8 + q;
      ff_s[r][cc] = fmaxf((pre_s[r][cc] - mean) * rstd * fu_g[cc] + fu_bb[cc], 0.f);
    }
  }
  __syncthreads();
  { // pr1 linear
    float bias = pr1_b[c];
    float a0 = bias, a1 = bias;
    for (int k = 0; k < 128; k++){
      float wv = pr1_wT[k * 128 + c];
      a0 += ff_s[q8][k] * wv;
      a1 += ff_s[q8 + 8][k] * wv;
    }
    pre_s[q8][c] = a0;
    pre_s[q8 + 8][c] = a1;
  }
  __syncthreads();
  if (t < 256){ // LN stats
    int r = t >> 4, j = t & 15;
    float s = 0.f, ss = 0.f;
    #pragma unroll
    for (int q = 0; q < 8; q++){ float v = pre_s[r][j + q * 16]; s += v; ss += v * v; }
    #pragma unroll
    for (int m = 1; m < 16; m <<= 1){ s += __shfl_xor(s, m, 64); ss += __shfl_xor(ss, m, 64); }
    if (j == 0){ float mean = s * (1.f / 128.f); stat[r][0] = mean;
                 stat[r][1] = rsqrtf(ss * (1.f / 128.f) - mean * mean + 1e-5f); }
  }
  __syncthreads();
  if (t < 256){
    int r = t >> 4, j = t & 15;
    float mean = stat[r][0], rstd = stat[r][1];
    #pragma unroll
    for (int q = 0; q < 8; q++){
      int cc = j * 8 + q;
      h_s[r][cc] = fmaxf((pre_s[r][cc] - mean) * rstd * pr_g[cc] + pr_bb[cc], 0.f);
    }
  }
  __syncthreads();
  if (t < 384){
    int lr = t / 24, cc = t % 24;
    float accp = pr2_b[cc], accg = rg_b[cc];
    for (int k = 0; k < 128; k++){
      accp += h_s[lr][k] * pr2_wT[k * 24 + cc];
      accg += ff_s[lr][k] * rg_wT[k * 24 + cc];
    }
    float gate = 1.f / (1.f + __expf(-accg));
    int n = n0 + lr;
    float xl = x[((size_t)b * 64 + 63) * 2048 + n];
    out[((size_t)b * 24 + cc) * 2048 + n] = gate * xl + (1.f - gate) * accp;
  }
  if (blockIdx.x == 0 && t == 0) out[2 * 24 * 2048] = 1e-4f / 2048.0f;  // reg
}

extern "C" void kernel_launch(void* const* d_in, const int* in_sizes, int n_in,
                              void* d_out, int out_size, void* d_ws, size_t ws_size,
                              hipStream_t stream){
  const float* x       = (const float*)d_in[0];
  const float* tc_w    = (const float*)d_in[1];
  const float* tc_b    = (const float*)d_in[2];
  const float* tc_bn_g = (const float*)d_in[3];
  const float* tc_bn_b = (const float*)d_in[4];
  const float* fp_w    = (const float*)d_in[5];
  const float* fp_b    = (const float*)d_in[6];
  const float* fp_ln_g = (const float*)d_in[7];
  const float* fp_ln_b = (const float*)d_in[8];
  const float* q_w     = (const float*)d_in[9];
  const float* q_b     = (const float*)d_in[10];
  const float* k_w     = (const float*)d_in[11];
  const float* k_b     = (const float*)d_in[12];
  const float* v_w     = (const float*)d_in[13];
  const float* v_b     = (const float*)d_in[14];
  const float* o_w     = (const float*)d_in[15];
  const float* o_b     = (const float*)d_in[16];
  const float* adj     = (const float*)d_in[17];
  const float* s0_w    = (const float*)d_in[18];
  const float* s0_b    = (const float*)d_in[19];
  const float* s0_bn_g = (const float*)d_in[20];
  const float* s0_bn_b = (const float*)d_in[21];
  const float* s1_w    = (const float*)d_in[22];
  const float* s1_b    = (const float*)d_in[23];
  const float* s1_bn_g = (const float*)d_in[24];
  const float* s1_bn_b = (const float*)d_in[25];
  const float* fusion_w= (const float*)d_in[26];
  const float* fu_w    = (const float*)d_in[27];
  const float* fu_b    = (const float*)d_in[28];
  const float* fu_ln_g = (const float*)d_in[29];
  const float* fu_ln_b = (const float*)d_in[30];
  const float* pr1_w   = (const float*)d_in[31];
  const float* pr1_b   = (const float*)d_in[32];
  const float* pr_ln_g = (const float*)d_in[33];
  const float* pr_ln_b = (const float*)d_in[34];
  const float* pr2_w   = (const float*)d_in[35];
  const float* pr2_b   = (const float*)d_in[36];
  const float* rg_w    = (const float*)d_in[37];
  const float* rg_b    = (const float*)d_in[38];
  float* out = (float*)d_out;

  char* ws = (char*)d_ws;
  size_t off = 0;
  auto alloc = [&](size_t bytes) -> void* {
    void* p = ws + off;
    off += (bytes + 255) & ~(size_t)255;
    return p;
  };
  unsigned short* fpw_bf  = (unsigned short*)alloc((size_t)128 * 2048 * 2);
  unsigned short* wcat_bf = (unsigned short*)alloc((size_t)384 * 128 * 2);
  unsigned short* q_bf    = (unsigned short*)alloc((size_t)16 * 2048 * 16 * 2);
  unsigned short* k_bf    = (unsigned short*)alloc((size_t)16 * 2048 * 16 * 2);
  unsigned short* vTp_bf  = (unsigned short*)alloc((size_t)16 * 2048 * 16 * 2);
  float* go     = (float*)alloc((size_t)4096 * 128 * 4);
  float* o_wT   = (float*)alloc(128 * 128 * 4);
  float* fu_wT  = (float*)alloc(128 * 128 * 4);
  float* pr1_wT = (float*)alloc(128 * 128 * 4);
  float* s0_wT  = (float*)alloc(128 * 128 * 4);
  float* s1_wT0 = (float*)alloc(128 * 128 * 4);
  float* s1_wT1 = (float*)alloc(128 * 128 * 4);
  float* pr2_wT = (float*)alloc(128 * 24 * 4);
  float* rg_wT  = (float*)alloc(128 * 24 * 4);
  if (off > ws_size) return;  // workspace too small (should not happen)

  prep_kernel<<<128, 256, 0, stream>>>(fp_w, q_w, k_w, v_w, o_w, s0_w, s1_w,
                                       fu_w, pr1_w, pr2_w, rg_w, fpw_bf, wcat_bf,
                                       o_wT, fu_wT, pr1_wT, s0_wT, s1_wT0, s1_wT1,
                                       pr2_wT, rg_wT);
  fused_feat_kernel<<<256, 512, 0, stream>>>(x, tc_w, tc_b, tc_bn_g, tc_bn_b,
                                             fpw_bf, fp_b, fp_ln_g, fp_ln_b,
                                             wcat_bf, q_b, k_b, v_b,
                                             q_bf, k_bf, vTp_bf);
  attn_kernel<<<1024, 256, 0, stream>>>(q_bf, k_bf, vTp_bf, adj, go);
  tail_kernel<<<256, 1024, 0, stream>>>(go, x, o_wT, o_b, s0_wT, s0_b, s0_bn_g, s0_bn_b,
                                        s1_wT0, s1_wT1, s1_b, s1_bn_g, s1_bn_b, fusion_w,
                                        fu_wT, fu_b, fu_ln_g, fu_ln_b, pr1_wT, pr1_b,
                                        pr_ln_g, pr_ln_b, pr2_wT, pr2_b, rg_wT, rg_b, out);
}

// Round 6
// 134.078 us; speedup vs baseline: 1.0830x; 1.0830x over previous
//
#include <hip/hip_runtime.h>

using f32x4  = __attribute__((ext_vector_type(4))) float;
using bf16x8 = __attribute__((ext_vector_type(8))) short;

#define DEV static __device__ __forceinline__

DEV unsigned short f2bf(float f){
  unsigned u = __float_as_uint(f);
  unsigned r = (u + 0x7FFFu + ((u >> 16) & 1u)) >> 16;
  return (unsigned short)r;
}

// vTp storage permutation: within each 64-n chunk, n=[h2|t|g1 g0|u1 u0] -> p=[h2|g1 g0|t|u1 u0]
DEV int vperm(int n){
  return (n & ~63) | (n & 32) | ((n & 0xC) << 1) | ((n & 0x10) >> 2) | (n & 3);
}

// ---------------- K0: weight prep (blocks 0..511) + temporal conv (512..1535)
__global__ __launch_bounds__(256) void prep_conv_kernel(
    const float* __restrict__ fp_w, const float* __restrict__ q_w,
    const float* __restrict__ k_w, const float* __restrict__ v_w,
    const float* __restrict__ o_w, const float* __restrict__ s0_w,
    const float* __restrict__ s1_w, const float* __restrict__ fu_w,
    const float* __restrict__ pr1_w, const float* __restrict__ pr2_w,
    const float* __restrict__ rg_w,
    unsigned short* __restrict__ fpw_bf, unsigned short* __restrict__ wcat_bf,
    float* __restrict__ o_wT, float* __restrict__ fu_wT, float* __restrict__ pr1_wT,
    float* __restrict__ s0_wT, float* __restrict__ s1_wT0, float* __restrict__ s1_wT1,
    float* __restrict__ pr2_wT, float* __restrict__ rg_wT,
    const float* __restrict__ x, const float* __restrict__ tc_w,
    const float* __restrict__ tc_b, const float* __restrict__ bn_g,
    const float* __restrict__ bn_b, unsigned short* __restrict__ f){
  if (blockIdx.x < 512){
    int i = blockIdx.x * 256 + threadIdx.x;
    const int stride = 512 * 256;
    for (int idx = i; idx < 128 * 2048; idx += stride) fpw_bf[idx] = f2bf(fp_w[idx]);
    for (int idx = i; idx < 384 * 128; idx += stride){
      int c = idx >> 7, k = idx & 127;
      float v;
      if (c < 128)      v = q_w[c * 128 + k] * 0.25f;   // fold 1/sqrt(hd)
      else if (c < 256) v = k_w[(c - 128) * 128 + k];
      else              v = v_w[(c - 256) * 128 + k];
      wcat_bf[idx] = f2bf(v);
    }
    for (int idx = i; idx < 128 * 128; idx += stride){
      int k = idx >> 7, c = idx & 127;
      o_wT[idx]   = o_w[c * 128 + k];
      fu_wT[idx]  = fu_w[c * 128 + k];
      pr1_wT[idx] = pr1_w[c * 128 + k];
      s0_wT[idx]  = s0_w[c * 128 + k];             // (o,i,1)
      s1_wT0[idx] = s1_w[(c * 128 + k) * 2 + 0];   // (o,i,2)
      s1_wT1[idx] = s1_w[(c * 128 + k) * 2 + 1];
    }
    for (int idx = i; idx < 128 * 24; idx += stride){
      int k = idx / 24, c = idx % 24;
      pr2_wT[idx] = pr2_w[c * 128 + k];
      rg_wT[idx]  = rg_w[c * 128 + k];
    }
  } else {
    int lane = threadIdx.x & 63;          // t = lane (T = 64)
    int w = threadIdx.x >> 6;
    int row = (blockIdx.x - 512) * 4 + w; // 0..4095 = b*2048+n
    int b = row >> 11, n = row & 2047;
    float xv = x[(size_t)(b * 64 + lane) * 2048 + n];
    float xm = __shfl_up(xv, 1, 64);   if (lane == 0)  xm = 0.f;
    float xp = __shfl_down(xv, 1, 64); if (lane == 63) xp = 0.f;
    const float inv = rsqrtf(1.0f + 1e-5f);
    unsigned short* frow = f + (size_t)row * 2048;
    #pragma unroll
    for (int c = 0; c < 32; c++){
      float y = xm * tc_w[c * 3 + 0] + xv * tc_w[c * 3 + 1] + xp * tc_w[c * 3 + 2] + tc_b[c];
      y = y * inv * bn_g[c] + bn_b[c];
      frow[c * 64 + lane] = f2bf(fmaxf(y, 0.f));
    }
  }
}

// ---------------- K1: feats = relu(LN(f @ fp_w^T + b)) + qkv, fused --------
__global__ __launch_bounds__(512) void featqkv_kernel(
    const unsigned short* __restrict__ f, const unsigned short* __restrict__ fpw,
    const float* __restrict__ fp_b, const float* __restrict__ ln_g,
    const float* __restrict__ ln_b,
    const unsigned short* __restrict__ wcat, const float* __restrict__ q_b,
    const float* __restrict__ k_b, const float* __restrict__ v_b,
    unsigned short* __restrict__ qo, unsigned short* __restrict__ ko,
    unsigned short* __restrict__ vTp){
  __shared__ float pre[16][128];
  __shared__ unsigned short ft[16 * 128];   // feats bf16, XOR-swizzled
  __shared__ float stat[16][2];
  int t = threadIdx.x;
  int lane = t & 63, w = t >> 6;            // w = 0..7
  int l15 = lane & 15, g = lane >> 4;
  int row0 = blockIdx.x * 16;
  int b = row0 >> 11, n0 = row0 & 2047;
  int c0 = w * 16;
  f32x4 acc = {0.f,0.f,0.f,0.f};
  const unsigned short* arow = f   + (size_t)(row0 + l15) * 2048 + g * 8;
  const unsigned short* bp   = fpw + (size_t)(c0 + l15) * 2048 + g * 8;
  #pragma unroll 4
  for (int k = 0; k < 2048; k += 32){
    bf16x8 a  = *(const bf16x8*)(arow + k);
    bf16x8 b0 = *(const bf16x8*)(bp + k);
    acc = __builtin_amdgcn_mfma_f32_16x16x32_bf16(a, b0, acc, 0, 0, 0);
  }
  #pragma unroll
  for (int r = 0; r < 4; r++)
    pre[g * 4 + r][c0 + l15] = acc[r] + fp_b[c0 + l15];
  __syncthreads();
  if (t < 256){
    int r = t >> 4, j = t & 15;
    float s = 0.f, ss = 0.f;
    #pragma unroll
    for (int q = 0; q < 8; q++){ float v = pre[r][j + q * 16]; s += v; ss += v * v; }
    #pragma unroll
    for (int m = 1; m < 16; m <<= 1){ s += __shfl_xor(s, m, 64); ss += __shfl_xor(ss, m, 64); }
    if (j == 0){
      float mean = s * (1.f / 128.f);
      stat[r][0] = mean;
      stat[r][1] = rsqrtf(ss * (1.f / 128.f) - mean * mean + 1e-5f);
    }
  }
  __syncthreads();
  if (t < 256){
    int r = t >> 4, j = t & 15;
    float mean = stat[r][0], rstd = stat[r][1];
    bf16x8 outv;
    #pragma unroll
    for (int q = 0; q < 8; q++){
      int cc = j * 8 + q;
      float v = (pre[r][cc] - mean) * rstd * ln_g[cc] + ln_b[cc];
      outv[q] = (short)f2bf(fmaxf(v, 0.f));
    }
    int byte = r * 256 + ((j * 16) ^ ((r & 7) << 4));
    *(bf16x8*)((char*)ft + byte) = outv;
  }
  __syncthreads();
  // qkv: 8 waves x 3 col-tiles of 16 = 384 output channels
  f32x4 acc3[3] = {{0,0,0,0},{0,0,0,0},{0,0,0,0}};
  #pragma unroll
  for (int kk = 0; kk < 128; kk += 32){
    int abyte = l15 * 256 + (((kk + g * 8) * 2) ^ ((l15 & 7) << 4));
    bf16x8 a = *(const bf16x8*)((const char*)ft + abyte);
    #pragma unroll
    for (int ci = 0; ci < 3; ci++){
      int cc0 = w * 48 + ci * 16;
      bf16x8 bb = *(const bf16x8*)(wcat + (size_t)(cc0 + l15) * 128 + g * 8 + kk);
      acc3[ci] = __builtin_amdgcn_mfma_f32_16x16x32_bf16(a, bb, acc3[ci], 0, 0, 0);
    }
  }
  #pragma unroll
  for (int ci = 0; ci < 3; ci++){
    int c = w * 48 + ci * 16 + l15;
    int mat = c >> 7, cm = c & 127;
    int hh = cm >> 4, d = cm & 15;
    float bias = (mat == 0) ? q_b[cm] * 0.25f : (mat == 1 ? k_b[cm] : v_b[cm]);
    int bh = b * 8 + hh;
    #pragma unroll
    for (int r = 0; r < 4; r++){
      int n = n0 + g * 4 + r;
      unsigned short bv = f2bf(acc3[ci][r] + bias);
      if (mat == 0)      qo[((size_t)bh * 2048 + n) * 16 + d] = bv;
      else if (mat == 1) ko[((size_t)bh * 2048 + n) * 16 + d] = bv;
      else               vTp[((size_t)bh * 16 + d) * 2048 + vperm(n)] = bv;
    }
  }
}

// ---------------- K2: attention, swapped-operand, 8-wave m-split -----------
__global__ __launch_bounds__(512) void attn_kernel(
    const unsigned short* __restrict__ qo, const unsigned short* __restrict__ ko,
    const unsigned short* __restrict__ vTp, const float* __restrict__ adj,
    float* __restrict__ go){
  __shared__ float red_acc[8][2][16][16];   // [w][b][d][q]
  __shared__ float red_rs[8][2][16];        // [w][b][q]
  int t = threadIdx.x, lane = t & 63, w = t >> 6;   // w = 0..7
  int l15 = lane & 15, g = lane >> 4;
  int h = blockIdx.x >> 7;                  // 0..7
  int row0 = (blockIdx.x & 127) * 16;       // 16 q-rows
  const bf16x8 zf = {0,0,0,0,0,0,0,0};
  const f32x4 z4 = {0.f,0.f,0.f,0.f};
  // B-operand Q fragment: lane col = q-row (l15), k = d (g*8..), pad g>=2
  bf16x8 qf[2];
  #pragma unroll
  for (int b2 = 0; b2 < 2; b2++){
    if (g < 2) qf[b2] = *(const bf16x8*)(qo + ((size_t)(b2 * 8 + h) * 2048 + row0 + l15) * 16 + g * 8);
    else       qf[b2] = zf;
  }
  f32x4 accv[2] = {{0.f,0.f,0.f,0.f},{0.f,0.f,0.f,0.f}};
  float rsp[2] = {0.f, 0.f};
  const float* adjrow = adj + ((size_t)h * 2048 + row0 + l15) * 2048 + g * 4;
  const int mbeg = w * 256;
  for (int m0 = mbeg; m0 < mbeg + 256; m0 += 64){
    f32x4 adjv[4];
    #pragma unroll
    for (int s = 0; s < 4; s++)
      adjv[s] = *(const f32x4*)(adjrow + m0 + s * 16);   // adj^T frag: vector load
    #pragma unroll
    for (int b2 = 0; b2 < 2; b2++){
      int bh = b2 * 8 + h;
      const unsigned short* kbase = ko + (size_t)bh * 2048 * 16;
      f32x4 sf[4];
      #pragma unroll
      for (int s = 0; s < 4; s++){
        bf16x8 kf;   // A-operand: lane row = K-row m (l15), k = d
        if (g < 2) kf = *(const bf16x8*)(kbase + (size_t)(m0 + s * 16 + l15) * 16 + g * 8);
        else       kf = zf;
        sf[s] = __builtin_amdgcn_mfma_f32_16x16x32_bf16(kf, qf[b2], z4, 0, 0, 0);
      }
      // S^T: lane (g,l15) holds S[m = m0+s*16+g*4+r][q = l15]
      bf16x8 pf[2];
      float partial = 0.f;
      #pragma unroll
      for (int s = 0; s < 4; s++){
        #pragma unroll
        for (int r = 0; r < 4; r++){
          float p = __expf(sf[s][r] + adjv[s][r]);   // tiny scores: no-max softmax
          partial += p;
          pf[s >> 1][(s & 1) * 4 + r] = (short)f2bf(p);
        }
      }
      rsp[b2] += partial;
      // PV: A = V^T (perm-stored, contiguous), B = lane-local packed P
      const unsigned short* vbase = vTp + ((size_t)bh * 16 + l15) * 2048 + m0;
      bf16x8 vf0 = *(const bf16x8*)(vbase + g * 8);
      bf16x8 vf1 = *(const bf16x8*)(vbase + 32 + g * 8);
      accv[b2] = __builtin_amdgcn_mfma_f32_16x16x32_bf16(vf0, pf[0], accv[b2], 0, 0, 0);
      accv[b2] = __builtin_amdgcn_mfma_f32_16x16x32_bf16(vf1, pf[1], accv[b2], 0, 0, 0);
    }
  }
  // reduce across g-groups (denominator) and across waves
  #pragma unroll
  for (int b2 = 0; b2 < 2; b2++){
    float s = rsp[b2];
    s += __shfl_xor(s, 16, 64);
    s += __shfl_xor(s, 32, 64);
    #pragma unroll
    for (int r = 0; r < 4; r++) red_acc[w][b2][g * 4 + r][l15] = accv[b2][r];
    if (lane < 16) red_rs[w][b2][l15] = s;
  }
  __syncthreads();
  {
    int b2 = t >> 8, qq = (t >> 4) & 15, d = t & 15;
    float v = 0.f, den = 0.f;
    #pragma unroll
    for (int ww = 0; ww < 8; ww++){ v += red_acc[ww][b2][d][qq]; den += red_rs[ww][b2][qq]; }
    go[((size_t)b2 * 2048 + row0 + qq) * 128 + h * 16 + d] = v / den;
  }
}

// ---------------- K3: o-proj + s0/s1 convs + interp + fusion + tail --------
__global__ __launch_bounds__(512) void tail_kernel(
    const float* __restrict__ go, const float* __restrict__ x,
    const float* __restrict__ o_wT, const float* __restrict__ o_b,
    const float* __restrict__ s0_wT, const float* __restrict__ s0_b,
    const float* __restrict__ s0_g, const float* __restrict__ s0_bb,
    const float* __restrict__ s1_wT0, const float* __restrict__ s1_wT1,
    const float* __restrict__ s1_b, const float* __restrict__ s1_g,
    const float* __restrict__ s1_bb, const float* __restrict__ fw,
    const float* __restrict__ fu_wT, const float* __restrict__ fu_b,
    const float* __restrict__ fu_g, const float* __restrict__ fu_bb,
    const float* __restrict__ pr1_wT, const float* __restrict__ pr1_b,
    const float* __restrict__ pr_g, const float* __restrict__ pr_bb,
    const float* __restrict__ pr2_wT, const float* __restrict__ pr2_b,
    const float* __restrict__ rg_wT, const float* __restrict__ rg_b,
    float* __restrict__ out){
  __shared__ float go_s[20][128];
  __shared__ float gf_s[21][128];
  __shared__ float f1_s[17][128];
  __shared__ float fu_in[16][128];
  __shared__ float pre_s[16][128];
  __shared__ float ff_s[16][128];
  __shared__ float h_s[16][128];
  __shared__ float stat[16][2];
  int t = threadIdx.x;
  int b = blockIdx.x >> 7;
  int n0 = (blockIdx.x & 127) * 16;
  for (int e = t; e < 20 * 128; e += 512){
    int lr = e >> 7, cc = e & 127;
    int gn = n0 - 1 + lr;
    go_s[lr][cc] = (lr < 18 && gn >= 0 && gn < 2048) ? go[((size_t)b * 2048 + gn) * 128 + cc] : 0.f;
  }
  __syncthreads();
  int c = t & 127, q4 = t >> 7;   // q4 = 0..3, rows strided i*4+q4
  const float bninv = rsqrtf(1.0f + 1e-5f);
  { // gf = go @ o_w^T + o_b  (rows 0..17 valid incl halo; zero outside)
    float acc[5];
    float bias = o_b[c];
    #pragma unroll
    for (int i = 0; i < 5; i++) acc[i] = bias;
    for (int k = 0; k < 128; k++){
      float wv = o_wT[k * 128 + c];
      #pragma unroll
      for (int i = 0; i < 5; i++) acc[i] += go_s[i * 4 + q4][k] * wv;
    }
    #pragma unroll
    for (int i = 0; i < 5; i++){
      int lr = i * 4 + q4;
      int gn = n0 - 1 + lr;
      gf_s[lr][c] = (lr < 18 && gn >= 0 && gn < 2048) ? acc[i] : 0.f;
    }
    if (t < 128) gf_s[20][t] = 0.f;
  }
  __syncthreads();
  { // f1[lr] = relu(bn1(w0*gf[lr] + w1*gf[lr+1])), rows 0..16
    float acc[5];
    float bias = s1_b[c];
    #pragma unroll
    for (int i = 0; i < 5; i++) acc[i] = bias;
    for (int k = 0; k < 128; k++){
      float w0 = s1_wT0[k * 128 + c], w1 = s1_wT1[k * 128 + c];
      #pragma unroll
      for (int i = 0; i < 5; i++)
        acc[i] += gf_s[i * 4 + q4][k] * w0 + gf_s[i * 4 + q4 + 1][k] * w1;
    }
    float sc = s1_g[c] * bninv, bb2 = s1_bb[c];
    #pragma unroll
    for (int i = 0; i < 5; i++){
      int lr = i * 4 + q4;
      if (lr < 17) f1_s[lr][c] = fmaxf(acc[i] * sc + bb2, 0.f);
    }
  }
  __syncthreads();
  { // fused = a0*f0 + a1*interp(f1), rows 0..15
    float acc[4];
    float bias = s0_b[c];
    #pragma unroll
    for (int i = 0; i < 4; i++) acc[i] = bias;
    for (int k = 0; k < 128; k++){
      float wv = s0_wT[k * 128 + c];
      #pragma unroll
      for (int i = 0; i < 4; i++) acc[i] += gf_s[i * 4 + q4 + 1][k] * wv;
    }
    float e0 = __expf(fw[0]), e1 = __expf(fw[1]);
    float a0 = e0 / (e0 + e1), a1 = e1 / (e0 + e1);
    float sc = s0_g[c] * bninv, bb2 = s0_bb[c];
    #pragma unroll
    for (int i = 0; i < 4; i++){
      int lr = i * 4 + q4;
      int n = n0 + lr;
      float f0 = fmaxf(acc[i] * sc + bb2, 0.f);
      float wn = (n + 0.5f) * (1.0f / 2048.0f);
      fu_in[lr][c] = a0 * f0 + a1 * ((1.f - wn) * f1_s[lr][c] + wn * f1_s[lr + 1][c]);
    }
  }
  __syncthreads();
  { // fu linear
    float acc[4];
    float bias = fu_b[c];
    #pragma unroll
    for (int i = 0; i < 4; i++) acc[i] = bias;
    for (int k = 0; k < 128; k++){
      float wv = fu_wT[k * 128 + c];
      #pragma unroll
      for (int i = 0; i < 4; i++) acc[i] += fu_in[i * 4 + q4][k] * wv;
    }
    #pragma unroll
    for (int i = 0; i < 4; i++) pre_s[i * 4 + q4][c] = acc[i];
  }
  __syncthreads();
  if (t < 256){ // LN stats
    int r = t >> 4, j = t & 15;
    float s = 0.f, ss = 0.f;
    #pragma unroll
    for (int q = 0; q < 8; q++){ float v = pre_s[r][j + q * 16]; s += v; ss += v * v; }
    #pragma unroll
    for (int m = 1; m < 16; m <<= 1){ s += __shfl_xor(s, m, 64); ss += __shfl_xor(ss, m, 64); }
    if (j == 0){ float mean = s * (1.f / 128.f); stat[r][0] = mean;
                 stat[r][1] = rsqrtf(ss * (1.f / 128.f) - mean * mean + 1e-5f); }
  }
  __syncthreads();
  if (t < 256){
    int r = t >> 4, j = t & 15;
    float mean = stat[r][0], rstd = stat[r][1];
    #pragma unroll
    for (int q = 0; q < 8; q++){
      int cc = j * 8 + q;
      ff_s[r][cc] = fmaxf((pre_s[r][cc] - mean) * rstd * fu_g[cc] + fu_bb[cc], 0.f);
    }
  }
  __syncthreads();
  { // pr1 linear
    float acc[4];
    float bias = pr1_b[c];
    #pragma unroll
    for (int i = 0; i < 4; i++) acc[i] = bias;
    for (int k = 0; k < 128; k++){
      float wv = pr1_wT[k * 128 + c];
      #pragma unroll
      for (int i = 0; i < 4; i++) acc[i] += ff_s[i * 4 + q4][k] * wv;
    }
    #pragma unroll
    for (int i = 0; i < 4; i++) pre_s[i * 4 + q4][c] = acc[i];
  }
  __syncthreads();
  if (t < 256){ // LN stats
    int r = t >> 4, j = t & 15;
    float s = 0.f, ss = 0.f;
    #pragma unroll
    for (int q = 0; q < 8; q++){ float v = pre_s[r][j + q * 16]; s += v; ss += v * v; }
    #pragma unroll
    for (int m = 1; m < 16; m <<= 1){ s += __shfl_xor(s, m, 64); ss += __shfl_xor(ss, m, 64); }
    if (j == 0){ float mean = s * (1.f / 128.f); stat[r][0] = mean;
                 stat[r][1] = rsqrtf(ss * (1.f / 128.f) - mean * mean + 1e-5f); }
  }
  __syncthreads();
  if (t < 256){
    int r = t >> 4, j = t & 15;
    float mean = stat[r][0], rstd = stat[r][1];
    #pragma unroll
    for (int q = 0; q < 8; q++){
      int cc = j * 8 + q;
      h_s[r][cc] = fmaxf((pre_s[r][cc] - mean) * rstd * pr_g[cc] + pr_bb[cc], 0.f);
    }
  }
  __syncthreads();
  if (t < 384){
    int lr = t / 24, cc = t % 24;
    float accp = pr2_b[cc], accg = rg_b[cc];
    for (int k = 0; k < 128; k++){
      accp += h_s[lr][k] * pr2_wT[k * 24 + cc];
      accg += ff_s[lr][k] * rg_wT[k * 24 + cc];
    }
    float gate = 1.f / (1.f + __expf(-accg));
    int n = n0 + lr;
    float xl = x[((size_t)b * 64 + 63) * 2048 + n];
    out[((size_t)b * 24 + cc) * 2048 + n] = gate * xl + (1.f - gate) * accp;
  }
  if (blockIdx.x == 0 && t == 0) out[2 * 24 * 2048] = 1e-4f / 2048.0f;  // reg
}

extern "C" void kernel_launch(void* const* d_in, const int* in_sizes, int n_in,
                              void* d_out, int out_size, void* d_ws, size_t ws_size,
                              hipStream_t stream){
  const float* x       = (const float*)d_in[0];
  const float* tc_w    = (const float*)d_in[1];
  const float* tc_b    = (const float*)d_in[2];
  const float* tc_bn_g = (const float*)d_in[3];
  const float* tc_bn_b = (const float*)d_in[4];
  const float* fp_w    = (const float*)d_in[5];
  const float* fp_b    = (const float*)d_in[6];
  const float* fp_ln_g = (const float*)d_in[7];
  const float* fp_ln_b = (const float*)d_in[8];
  const float* q_w     = (const float*)d_in[9];
  const float* q_b     = (const float*)d_in[10];
  const float* k_w     = (const float*)d_in[11];
  const float* k_b     = (const float*)d_in[12];
  const float* v_w     = (const float*)d_in[13];
  const float* v_b     = (const float*)d_in[14];
  const float* o_w     = (const float*)d_in[15];
  const float* o_b     = (const float*)d_in[16];
  const float* adj     = (const float*)d_in[17];
  const float* s0_w    = (const float*)d_in[18];
  const float* s0_b    = (const float*)d_in[19];
  const float* s0_bn_g = (const float*)d_in[20];
  const float* s0_bn_b = (const float*)d_in[21];
  const float* s1_w    = (const float*)d_in[22];
  const float* s1_b    = (const float*)d_in[23];
  const float* s1_bn_g = (const float*)d_in[24];
  const float* s1_bn_b = (const float*)d_in[25];
  const float* fusion_w= (const float*)d_in[26];
  const float* fu_w    = (const float*)d_in[27];
  const float* fu_b    = (const float*)d_in[28];
  const float* fu_ln_g = (const float*)d_in[29];
  const float* fu_ln_b = (const float*)d_in[30];
  const float* pr1_w   = (const float*)d_in[31];
  const float* pr1_b   = (const float*)d_in[32];
  const float* pr_ln_g = (const float*)d_in[33];
  const float* pr_ln_b = (const float*)d_in[34];
  const float* pr2_w   = (const float*)d_in[35];
  const float* pr2_b   = (const float*)d_in[36];
  const float* rg_w    = (const float*)d_in[37];
  const float* rg_b    = (const float*)d_in[38];
  float* out = (float*)d_out;

  char* ws = (char*)d_ws;
  size_t off = 0;
  auto alloc = [&](size_t bytes) -> void* {
    void* p = ws + off;
    off += (bytes + 255) & ~(size_t)255;
    return p;
  };
  unsigned short* f_bf    = (unsigned short*)alloc((size_t)4096 * 2048 * 2);
  unsigned short* fpw_bf  = (unsigned short*)alloc((size_t)128 * 2048 * 2);
  unsigned short* wcat_bf = (unsigned short*)alloc((size_t)384 * 128 * 2);
  unsigned short* q_bf    = (unsigned short*)alloc((size_t)16 * 2048 * 16 * 2);
  unsigned short* k_bf    = (unsigned short*)alloc((size_t)16 * 2048 * 16 * 2);
  unsigned short* vTp_bf  = (unsigned short*)alloc((size_t)16 * 2048 * 16 * 2);
  float* go     = (float*)alloc((size_t)4096 * 128 * 4);
  float* o_wT   = (float*)alloc(128 * 128 * 4);
  float* fu_wT  = (float*)alloc(128 * 128 * 4);
  float* pr1_wT = (float*)alloc(128 * 128 * 4);
  float* s0_wT  = (float*)alloc(128 * 128 * 4);
  float* s1_wT0 = (float*)alloc(128 * 128 * 4);
  float* s1_wT1 = (float*)alloc(128 * 128 * 4);
  float* pr2_wT = (float*)alloc(128 * 24 * 4);
  float* rg_wT  = (float*)alloc(128 * 24 * 4);
  if (off > ws_size) return;  // workspace too small (should not happen)

  prep_conv_kernel<<<1536, 256, 0, stream>>>(fp_w, q_w, k_w, v_w, o_w, s0_w, s1_w,
                                             fu_w, pr1_w, pr2_w, rg_w, fpw_bf, wcat_bf,
                                             o_wT, fu_wT, pr1_wT, s0_wT, s1_wT0, s1_wT1,
                                             pr2_wT, rg_wT,
                                             x, tc_w, tc_b, tc_bn_g, tc_bn_b, f_bf);
  featqkv_kernel<<<256, 512, 0, stream>>>(f_bf, fpw_bf, fp_b, fp_ln_g, fp_ln_b,
                                          wcat_bf, q_b, k_b, v_b, q_bf, k_bf, vTp_bf);
  attn_kernel<<<1024, 512, 0, stream>>>(q_bf, k_bf, vTp_bf, adj, go);
  tail_kernel<<<256, 512, 0, stream>>>(go, x, o_wT, o_b, s0_wT, s0_b, s0_bn_g, s0_bn_b,
                                       s1_wT0, s1_wT1, s1_b, s1_bn_g, s1_bn_b, fusion_w,
                                       fu_wT, fu_b, fu_ln_g, fu_ln_b, pr1_wT, pr1_b,
                                       pr_ln_g, pr_ln_b, pr2_wT, pr2_b, rg_wT, rg_b, out);
}

// Round 7
// 124.095 us; speedup vs baseline: 1.1702x; 1.0804x over previous
//
#include <hip/hip_runtime.h>

using f32x4  = __attribute__((ext_vector_type(4))) float;
using bf16x8 = __attribute__((ext_vector_type(8))) short;

#define DEV static __device__ __forceinline__

DEV unsigned short f2bf(float f){
  unsigned u = __float_as_uint(f);
  unsigned r = (u + 0x7FFFu + ((u >> 16) & 1u)) >> 16;
  return (unsigned short)r;
}

// vTp storage permutation: within each 64-n chunk, n=[h2|t|g1 g0|u1 u0] -> p=[h2|g1 g0|t|u1 u0]
DEV int vperm(int n){
  return (n & ~63) | (n & 32) | ((n & 0xC) << 1) | ((n & 0x10) >> 2) | (n & 3);
}

// ---------------- K0: weight prep ------------------------------------------
__global__ __launch_bounds__(256) void prep_kernel(
    const float* __restrict__ fp_w, const float* __restrict__ q_w,
    const float* __restrict__ k_w, const float* __restrict__ v_w,
    const float* __restrict__ o_w, const float* __restrict__ s0_w,
    const float* __restrict__ s1_w, const float* __restrict__ fu_w,
    const float* __restrict__ pr1_w, const float* __restrict__ pr2_w,
    const float* __restrict__ rg_w,
    unsigned short* __restrict__ fpw_bf, unsigned short* __restrict__ wcat_bf,
    float* __restrict__ o_wT, float* __restrict__ fu_wT, float* __restrict__ pr1_wT,
    float* __restrict__ s0_wT, float* __restrict__ s1_wT0, float* __restrict__ s1_wT1,
    float* __restrict__ pr2_wT, float* __restrict__ rg_wT){
  int i = blockIdx.x * 256 + threadIdx.x;
  const int stride = 128 * 256;
  for (int idx = i; idx < 128 * 2048; idx += stride) fpw_bf[idx] = f2bf(fp_w[idx]);
  for (int idx = i; idx < 384 * 128; idx += stride){
    int c = idx >> 7, k = idx & 127;
    float v;
    if (c < 128)      v = q_w[c * 128 + k] * 0.25f;   // fold 1/sqrt(hd)
    else if (c < 256) v = k_w[(c - 128) * 128 + k];
    else              v = v_w[(c - 256) * 128 + k];
    wcat_bf[idx] = f2bf(v);
  }
  for (int idx = i; idx < 128 * 128; idx += stride){
    int k = idx >> 7, c = idx & 127;
    o_wT[idx]   = o_w[c * 128 + k];
    fu_wT[idx]  = fu_w[c * 128 + k];
    pr1_wT[idx] = pr1_w[c * 128 + k];
    s0_wT[idx]  = s0_w[c * 128 + k];             // (o,i,1)
    s1_wT0[idx] = s1_w[(c * 128 + k) * 2 + 0];   // (o,i,2)
    s1_wT1[idx] = s1_w[(c * 128 + k) * 2 + 1];
  }
  for (int idx = i; idx < 128 * 24; idx += stride){
    int k = idx / 24, c = idx % 24;
    pr2_wT[idx] = pr2_w[c * 128 + k];
    rg_wT[idx]  = rg_w[c * 128 + k];
  }
}

// ---------------- K1: conv + feat GEMM + LN + qkv, fused (no f round-trip) -
__global__ __launch_bounds__(512) void convfeatqkv_kernel(
    const float* __restrict__ x, const float* __restrict__ tc_w,
    const float* __restrict__ tc_b, const float* __restrict__ bn_g,
    const float* __restrict__ bn_b,
    const unsigned short* __restrict__ fpw, const float* __restrict__ fp_b,
    const float* __restrict__ ln_g, const float* __restrict__ ln_b,
    const unsigned short* __restrict__ wcat, const float* __restrict__ q_b,
    const float* __restrict__ k_b, const float* __restrict__ v_b,
    unsigned short* __restrict__ qo, unsigned short* __restrict__ ko,
    unsigned short* __restrict__ vTp){
  __shared__ float xs[64][17];               // x tile (t, n)
  __shared__ unsigned short fs[16 * 1024];   // one K-half of A-panel, XOR-swizzled (32 KB)
  __shared__ float pre[16][128];
  __shared__ unsigned short ft[16 * 128];    // feats bf16, XOR-swizzled
  __shared__ float stat[16][2];
  int t = threadIdx.x;
  int lane = t & 63, w = t >> 6;             // w = 0..7
  int l15 = lane & 15, g = lane >> 4;
  int row0 = blockIdx.x * 16;
  int b = row0 >> 11, n0 = row0 & 2047;
  const float bninv = rsqrtf(1.0f + 1e-5f);
  for (int e = t; e < 1024; e += 512){
    int tt = e >> 4, nn2 = e & 15;
    xs[tt][nn2] = x[(size_t)(b * 64 + tt) * 2048 + n0 + nn2];
  }
  __syncthreads();
  // conv thread mapping: nn = t&15, chl = (t>>4)&15 (channel within half), th = t>>8
  int nn = t & 15, chl = (t >> 4) & 15, th = t >> 8;   // th = 0..1: t'-range
  int c0 = w * 16;
  f32x4 acc = {0.f,0.f,0.f,0.f};
  const unsigned short* bp = fpw + (size_t)(c0 + l15) * 2048 + g * 8;
  const char* fsbase = (const char*)fs + l15 * 2048;
  int aswz = (l15 & 7) << 4;
  char* fsrow = (char*)fs + nn * 2048;
  int wswz = (nn & 7) << 4;
  for (int half = 0; half < 2; half++){
    { // conv: 16 ch x 16 nn x 2 t-halves = 512 threads fully used
      int ch = half * 16 + chl;
      float cw0 = tc_w[ch * 3 + 0], cw1 = tc_w[ch * 3 + 1], cw2 = tc_w[ch * 3 + 2];
      float cb = tc_b[ch];
      float csc = bninv * bn_g[ch], cbb = bn_b[ch];
      int t0 = th * 32;
      float xprev = (t0 > 0) ? xs[t0 - 1][nn] : 0.f;
      float xcur  = xs[t0][nn];
      #pragma unroll
      for (int j = 0; j < 4; j++){
        bf16x8 pack;
        #pragma unroll
        for (int i2 = 0; i2 < 8; i2++){
          int tt = t0 + j * 8 + i2;
          float xnext = (tt < 63) ? xs[tt + 1][nn] : 0.f;
          float y = (xprev * cw0 + xcur * cw1 + xnext * cw2 + cb) * csc + cbb;
          pack[i2] = (short)f2bf(fmaxf(y, 0.f));
          xprev = xcur; xcur = xnext;
        }
        int kl = chl * 64 + t0 + j * 8;      // K index within half
        *(bf16x8*)(fsrow + ((kl * 2) ^ wswz)) = pack;
      }
    }
    __syncthreads();
    #pragma unroll 4
    for (int kk = 0; kk < 1024; kk += 32){
      bf16x8 a  = *(const bf16x8*)(fsbase + (((kk + g * 8) * 2) ^ aswz));
      bf16x8 b0 = *(const bf16x8*)(bp + half * 1024 + kk);
      acc = __builtin_amdgcn_mfma_f32_16x16x32_bf16(a, b0, acc, 0, 0, 0);
    }
    __syncthreads();   // fs reused next half
  }
  #pragma unroll
  for (int r = 0; r < 4; r++)
    pre[g * 4 + r][c0 + l15] = acc[r] + fp_b[c0 + l15];
  __syncthreads();
  if (t < 256){
    int r = t >> 4, j = t & 15;
    float s = 0.f, ss = 0.f;
    #pragma unroll
    for (int q = 0; q < 8; q++){ float v = pre[r][j + q * 16]; s += v; ss += v * v; }
    #pragma unroll
    for (int m = 1; m < 16; m <<= 1){ s += __shfl_xor(s, m, 64); ss += __shfl_xor(ss, m, 64); }
    if (j == 0){
      float mean = s * (1.f / 128.f);
      stat[r][0] = mean;
      stat[r][1] = rsqrtf(ss * (1.f / 128.f) - mean * mean + 1e-5f);
    }
  }
  __syncthreads();
  if (t < 256){
    int r = t >> 4, j = t & 15;
    float mean = stat[r][0], rstd = stat[r][1];
    bf16x8 outv;
    #pragma unroll
    for (int q = 0; q < 8; q++){
      int cc = j * 8 + q;
      float v = (pre[r][cc] - mean) * rstd * ln_g[cc] + ln_b[cc];
      outv[q] = (short)f2bf(fmaxf(v, 0.f));
    }
    int byte = r * 256 + ((j * 16) ^ ((r & 7) << 4));
    *(bf16x8*)((char*)ft + byte) = outv;
  }
  __syncthreads();
  // qkv: 8 waves x 3 col-tiles of 16 = 384 output channels
  f32x4 acc3[3] = {{0,0,0,0},{0,0,0,0},{0,0,0,0}};
  #pragma unroll
  for (int kk = 0; kk < 128; kk += 32){
    int abyte = l15 * 256 + (((kk + g * 8) * 2) ^ ((l15 & 7) << 4));
    bf16x8 a = *(const bf16x8*)((const char*)ft + abyte);
    #pragma unroll
    for (int ci = 0; ci < 3; ci++){
      int cc0 = w * 48 + ci * 16;
      bf16x8 bb = *(const bf16x8*)(wcat + (size_t)(cc0 + l15) * 128 + g * 8 + kk);
      acc3[ci] = __builtin_amdgcn_mfma_f32_16x16x32_bf16(a, bb, acc3[ci], 0, 0, 0);
    }
  }
  #pragma unroll
  for (int ci = 0; ci < 3; ci++){
    int c = w * 48 + ci * 16 + l15;
    int mat = c >> 7, cm = c & 127;
    int hh = cm >> 4, d = cm & 15;
    float bias = (mat == 0) ? q_b[cm] * 0.25f : (mat == 1 ? k_b[cm] : v_b[cm]);
    int bh = b * 8 + hh;
    #pragma unroll
    for (int r = 0; r < 4; r++){
      int n = n0 + g * 4 + r;
      unsigned short bv = f2bf(acc3[ci][r] + bias);
      if (mat == 0)      qo[((size_t)bh * 2048 + n) * 16 + d] = bv;
      else if (mat == 1) ko[((size_t)bh * 2048 + n) * 16 + d] = bv;
      else               vTp[((size_t)bh * 16 + d) * 2048 + vperm(n)] = bv;
    }
  }
}

// ---------------- K2: attention, swapped-operand, 8-wave m-split -----------
__global__ __launch_bounds__(512) void attn_kernel(
    const unsigned short* __restrict__ qo, const unsigned short* __restrict__ ko,
    const unsigned short* __restrict__ vTp, const float* __restrict__ adj,
    float* __restrict__ go){
  __shared__ float red_acc[8][2][16][16];   // [w][b][d][q]
  __shared__ float red_rs[8][2][16];        // [w][b][q]
  int t = threadIdx.x, lane = t & 63, w = t >> 6;   // w = 0..7
  int l15 = lane & 15, g = lane >> 4;
  int h = blockIdx.x >> 7;                  // 0..7
  int row0 = (blockIdx.x & 127) * 16;       // 16 q-rows
  const bf16x8 zf = {0,0,0,0,0,0,0,0};
  const f32x4 z4 = {0.f,0.f,0.f,0.f};
  bf16x8 qf[2];
  #pragma unroll
  for (int b2 = 0; b2 < 2; b2++){
    if (g < 2) qf[b2] = *(const bf16x8*)(qo + ((size_t)(b2 * 8 + h) * 2048 + row0 + l15) * 16 + g * 8);
    else       qf[b2] = zf;
  }
  f32x4 accv[2] = {{0.f,0.f,0.f,0.f},{0.f,0.f,0.f,0.f}};
  float rsp[2] = {0.f, 0.f};
  const float* adjrow = adj + ((size_t)h * 2048 + row0 + l15) * 2048 + g * 4;
  const int mbeg = w * 256;
  for (int m0 = mbeg; m0 < mbeg + 256; m0 += 64){
    f32x4 adjv[4];
    #pragma unroll
    for (int s = 0; s < 4; s++)
      adjv[s] = *(const f32x4*)(adjrow + m0 + s * 16);   // adj^T frag: vector load
    #pragma unroll
    for (int b2 = 0; b2 < 2; b2++){
      int bh = b2 * 8 + h;
      const unsigned short* kbase = ko + (size_t)bh * 2048 * 16;
      f32x4 sf[4];
      #pragma unroll
      for (int s = 0; s < 4; s++){
        bf16x8 kf;   // A-operand: lane row = K-row m (l15), k = d
        if (g < 2) kf = *(const bf16x8*)(kbase + (size_t)(m0 + s * 16 + l15) * 16 + g * 8);
        else       kf = zf;
        sf[s] = __builtin_amdgcn_mfma_f32_16x16x32_bf16(kf, qf[b2], z4, 0, 0, 0);
      }
      // S^T: lane (g,l15) holds S[m = m0+s*16+g*4+r][q = l15]
      bf16x8 pf[2];
      float partial = 0.f;
      #pragma unroll
      for (int s = 0; s < 4; s++){
        #pragma unroll
        for (int r = 0; r < 4; r++){
          float p = __expf(sf[s][r] + adjv[s][r]);   // tiny scores: no-max softmax
          partial += p;
          pf[s >> 1][(s & 1) * 4 + r] = (short)f2bf(p);
        }
      }
      rsp[b2] += partial;
      // PV: A = V^T (perm-stored, contiguous), B = lane-local packed P
      const unsigned short* vbase = vTp + ((size_t)bh * 16 + l15) * 2048 + m0;
      bf16x8 vf0 = *(const bf16x8*)(vbase + g * 8);
      bf16x8 vf1 = *(const bf16x8*)(vbase + 32 + g * 8);
      accv[b2] = __builtin_amdgcn_mfma_f32_16x16x32_bf16(vf0, pf[0], accv[b2], 0, 0, 0);
      accv[b2] = __builtin_amdgcn_mfma_f32_16x16x32_bf16(vf1, pf[1], accv[b2], 0, 0, 0);
    }
  }
  #pragma unroll
  for (int b2 = 0; b2 < 2; b2++){
    float s = rsp[b2];
    s += __shfl_xor(s, 16, 64);
    s += __shfl_xor(s, 32, 64);
    #pragma unroll
    for (int r = 0; r < 4; r++) red_acc[w][b2][g * 4 + r][l15] = accv[b2][r];
    if (lane < 16) red_rs[w][b2][l15] = s;
  }
  __syncthreads();
  {
    int b2 = t >> 8, qq = (t >> 4) & 15, d = t & 15;
    float v = 0.f, den = 0.f;
    #pragma unroll
    for (int ww = 0; ww < 8; ww++){ v += red_acc[ww][b2][d][qq]; den += red_rs[ww][b2][qq]; }
    go[((size_t)b2 * 2048 + row0 + qq) * 128 + h * 16 + d] = v / den;
  }
}

// ---------------- K3: o-proj + s0/s1 convs + interp + fusion + tail --------
__global__ __launch_bounds__(512) void tail_kernel(
    const float* __restrict__ go, const float* __restrict__ x,
    const float* __restrict__ o_wT, const float* __restrict__ o_b,
    const float* __restrict__ s0_wT, const float* __restrict__ s0_b,
    const float* __restrict__ s0_g, const float* __restrict__ s0_bb,
    const float* __restrict__ s1_wT0, const float* __restrict__ s1_wT1,
    const float* __restrict__ s1_b, const float* __restrict__ s1_g,
    const float* __restrict__ s1_bb, const float* __restrict__ fw,
    const float* __restrict__ fu_wT, const float* __restrict__ fu_b,
    const float* __restrict__ fu_g, const float* __restrict__ fu_bb,
    const float* __restrict__ pr1_wT, const float* __restrict__ pr1_b,
    const float* __restrict__ pr_g, const float* __restrict__ pr_bb,
    const float* __restrict__ pr2_wT, const float* __restrict__ pr2_b,
    const float* __restrict__ rg_wT, const float* __restrict__ rg_b,
    float* __restrict__ out){
  __shared__ float go_s[20][128];
  __shared__ float gf_s[21][128];
  __shared__ float f1_s[17][128];
  __shared__ float fu_in[16][128];
  __shared__ float pre_s[16][128];
  __shared__ float ff_s[16][128];
  __shared__ float h_s[16][128];
  __shared__ float stat[16][2];
  int t = threadIdx.x;
  int b = blockIdx.x >> 7;
  int n0 = (blockIdx.x & 127) * 16;
  for (int e = t; e < 20 * 128; e += 512){
    int lr = e >> 7, cc = e & 127;
    int gn = n0 - 1 + lr;
    go_s[lr][cc] = (lr < 18 && gn >= 0 && gn < 2048) ? go[((size_t)b * 2048 + gn) * 128 + cc] : 0.f;
  }
  __syncthreads();
  int c = t & 127, q4 = t >> 7;   // q4 = 0..3, rows strided i*4+q4
  const float bninv = rsqrtf(1.0f + 1e-5f);
  { // gf = go @ o_w^T + o_b  (rows 0..17 valid incl halo; zero outside)
    float acc[5];
    float bias = o_b[c];
    #pragma unroll
    for (int i = 0; i < 5; i++) acc[i] = bias;
    for (int k = 0; k < 128; k++){
      float wv = o_wT[k * 128 + c];
      #pragma unroll
      for (int i = 0; i < 5; i++) acc[i] += go_s[i * 4 + q4][k] * wv;
    }
    #pragma unroll
    for (int i = 0; i < 5; i++){
      int lr = i * 4 + q4;
      int gn = n0 - 1 + lr;
      gf_s[lr][c] = (lr < 18 && gn >= 0 && gn < 2048) ? acc[i] : 0.f;
    }
    if (t < 128) gf_s[20][t] = 0.f;
  }
  __syncthreads();
  { // f1[lr] = relu(bn1(w0*gf[lr] + w1*gf[lr+1])), rows 0..16
    float acc[5];
    float bias = s1_b[c];
    #pragma unroll
    for (int i = 0; i < 5; i++) acc[i] = bias;
    for (int k = 0; k < 128; k++){
      float w0 = s1_wT0[k * 128 + c], w1 = s1_wT1[k * 128 + c];
      #pragma unroll
      for (int i = 0; i < 5; i++)
        acc[i] += gf_s[i * 4 + q4][k] * w0 + gf_s[i * 4 + q4 + 1][k] * w1;
    }
    float sc = s1_g[c] * bninv, bb2 = s1_bb[c];
    #pragma unroll
    for (int i = 0; i < 5; i++){
      int lr = i * 4 + q4;
      if (lr < 17) f1_s[lr][c] = fmaxf(acc[i] * sc + bb2, 0.f);
    }
  }
  __syncthreads();
  { // fused = a0*f0 + a1*interp(f1), rows 0..15
    float acc[4];
    float bias = s0_b[c];
    #pragma unroll
    for (int i = 0; i < 4; i++) acc[i] = bias;
    for (int k = 0; k < 128; k++){
      float wv = s0_wT[k * 128 + c];
      #pragma unroll
      for (int i = 0; i < 4; i++) acc[i] += gf_s[i * 4 + q4 + 1][k] * wv;
    }
    float e0 = __expf(fw[0]), e1 = __expf(fw[1]);
    float a0 = e0 / (e0 + e1), a1 = e1 / (e0 + e1);
    float sc = s0_g[c] * bninv, bb2 = s0_bb[c];
    #pragma unroll
    for (int i = 0; i < 4; i++){
      int lr = i * 4 + q4;
      int n = n0 + lr;
      float f0 = fmaxf(acc[i] * sc + bb2, 0.f);
      float wn = (n + 0.5f) * (1.0f / 2048.0f);
      fu_in[lr][c] = a0 * f0 + a1 * ((1.f - wn) * f1_s[lr][c] + wn * f1_s[lr + 1][c]);
    }
  }
  __syncthreads();
  { // fu linear
    float acc[4];
    float bias = fu_b[c];
    #pragma unroll
    for (int i = 0; i < 4; i++) acc[i] = bias;
    for (int k = 0; k < 128; k++){
      float wv = fu_wT[k * 128 + c];
      #pragma unroll
      for (int i = 0; i < 4; i++) acc[i] += fu_in[i * 4 + q4][k] * wv;
    }
    #pragma unroll
    for (int i = 0; i < 4; i++) pre_s[i * 4 + q4][c] = acc[i];
  }
  __syncthreads();
  if (t < 256){ // LN stats
    int r = t >> 4, j = t & 15;
    float s = 0.f, ss = 0.f;
    #pragma unroll
    for (int q = 0; q < 8; q++){ float v = pre_s[r][j + q * 16]; s += v; ss += v * v; }
    #pragma unroll
    for (int m = 1; m < 16; m <<= 1){ s += __shfl_xor(s, m, 64); ss += __shfl_xor(ss, m, 64); }
    if (j == 0){ float mean = s * (1.f / 128.f); stat[r][0] = mean;
                 stat[r][1] = rsqrtf(ss * (1.f / 128.f) - mean * mean + 1e-5f); }
  }
  __syncthreads();
  if (t < 256){
    int r = t >> 4, j = t & 15;
    float mean = stat[r][0], rstd = stat[r][1];
    #pragma unroll
    for (int q = 0; q < 8; q++){
      int cc = j * 8 + q;
      ff_s[r][cc] = fmaxf((pre_s[r][cc] - mean) * rstd * fu_g[cc] + fu_bb[cc], 0.f);
    }
  }
  __syncthreads();
  { // pr1 linear
    float acc[4];
    float bias = pr1_b[c];
    #pragma unroll
    for (int i = 0; i < 4; i++) acc[i] = bias;
    for (int k = 0; k < 128; k++){
      float wv = pr1_wT[k * 128 + c];
      #pragma unroll
      for (int i = 0; i < 4; i++) acc[i] += ff_s[i * 4 + q4][k] * wv;
    }
    #pragma unroll
    for (int i = 0; i < 4; i++) pre_s[i * 4 + q4][c] = acc[i];
  }
  __syncthreads();
  if (t < 256){ // LN stats
    int r = t >> 4, j = t & 15;
    float s = 0.f, ss = 0.f;
    #pragma unroll
    for (int q = 0; q < 8; q++){ float v = pre_s[r][j + q * 16]; s += v; ss += v * v; }
    #pragma unroll
    for (int m = 1; m < 16; m <<= 1){ s += __shfl_xor(s, m, 64); ss += __shfl_xor(ss, m, 64); }
    if (j == 0){ float mean = s * (1.f / 128.f); stat[r][0] = mean;
                 stat[r][1] = rsqrtf(ss * (1.f / 128.f) - mean * mean + 1e-5f); }
  }
  __syncthreads();
  if (t < 256){
    int r = t >> 4, j = t & 15;
    float mean = stat[r][0], rstd = stat[r][1];
    #pragma unroll
    for (int q = 0; q < 8; q++){
      int cc = j * 8 + q;
      h_s[r][cc] = fmaxf((pre_s[r][cc] - mean) * rstd * pr_g[cc] + pr_bb[cc], 0.f);
    }
  }
  __syncthreads();
  if (t < 384){
    int lr = t / 24, cc = t % 24;
    float accp = pr2_b[cc], accg = rg_b[cc];
    for (int k = 0; k < 128; k++){
      accp += h_s[lr][k] * pr2_wT[k * 24 + cc];
      accg += ff_s[lr][k] * rg_wT[k * 24 + cc];
    }
    float gate = 1.f / (1.f + __expf(-accg));
    int n = n0 + lr;
    float xl = x[((size_t)b * 64 + 63) * 2048 + n];
    out[((size_t)b * 24 + cc) * 2048 + n] = gate * xl + (1.f - gate) * accp;
  }
  if (blockIdx.x == 0 && t == 0) out[2 * 24 * 2048] = 1e-4f / 2048.0f;  // reg
}

extern "C" void kernel_launch(void* const* d_in, const int* in_sizes, int n_in,
                              void* d_out, int out_size, void* d_ws, size_t ws_size,
                              hipStream_t stream){
  const float* x       = (const float*)d_in[0];
  const float* tc_w    = (const float*)d_in[1];
  const float* tc_b    = (const float*)d_in[2];
  const float* tc_bn_g = (const float*)d_in[3];
  const float* tc_bn_b = (const float*)d_in[4];
  const float* fp_w    = (const float*)d_in[5];
  const float* fp_b    = (const float*)d_in[6];
  const float* fp_ln_g = (const float*)d_in[7];
  const float* fp_ln_b = (const float*)d_in[8];
  const float* q_w     = (const float*)d_in[9];
  const float* q_b     = (const float*)d_in[10];
  const float* k_w     = (const float*)d_in[11];
  const float* k_b     = (const float*)d_in[12];
  const float* v_w     = (const float*)d_in[13];
  const float* v_b     = (const float*)d_in[14];
  const float* o_w     = (const float*)d_in[15];
  const float* o_b     = (const float*)d_in[16];
  const float* adj     = (const float*)d_in[17];
  const float* s0_w    = (const float*)d_in[18];
  const float* s0_b    = (const float*)d_in[19];
  const float* s0_bn_g = (const float*)d_in[20];
  const float* s0_bn_b = (const float*)d_in[21];
  const float* s1_w    = (const float*)d_in[22];
  const float* s1_b    = (const float*)d_in[23];
  const float* s1_bn_g = (const float*)d_in[24];
  const float* s1_bn_b = (const float*)d_in[25];
  const float* fusion_w= (const float*)d_in[26];
  const float* fu_w    = (const float*)d_in[27];
  const float* fu_b    = (const float*)d_in[28];
  const float* fu_ln_g = (const float*)d_in[29];
  const float* fu_ln_b = (const float*)d_in[30];
  const float* pr1_w   = (const float*)d_in[31];
  const float* pr1_b   = (const float*)d_in[32];
  const float* pr_ln_g = (const float*)d_in[33];
  const float* pr_ln_b = (const float*)d_in[34];
  const float* pr2_w   = (const float*)d_in[35];
  const float* pr2_b   = (const float*)d_in[36];
  const float* rg_w    = (const float*)d_in[37];
  const float* rg_b    = (const float*)d_in[38];
  float* out = (float*)d_out;

  char* ws = (char*)d_ws;
  size_t off = 0;
  auto alloc = [&](size_t bytes) -> void* {
    void* p = ws + off;
    off += (bytes + 255) & ~(size_t)255;
    return p;
  };
  unsigned short* fpw_bf  = (unsigned short*)alloc((size_t)128 * 2048 * 2);
  unsigned short* wcat_bf = (unsigned short*)alloc((size_t)384 * 128 * 2);
  unsigned short* q_bf    = (unsigned short*)alloc((size_t)16 * 2048 * 16 * 2);
  unsigned short* k_bf    = (unsigned short*)alloc((size_t)16 * 2048 * 16 * 2);
  unsigned short* vTp_bf  = (unsigned short*)alloc((size_t)16 * 2048 * 16 * 2);
  float* go     = (float*)alloc((size_t)4096 * 128 * 4);
  float* o_wT   = (float*)alloc(128 * 128 * 4);
  float* fu_wT  = (float*)alloc(128 * 128 * 4);
  float* pr1_wT = (float*)alloc(128 * 128 * 4);
  float* s0_wT  = (float*)alloc(128 * 128 * 4);
  float* s1_wT0 = (float*)alloc(128 * 128 * 4);
  float* s1_wT1 = (float*)alloc(128 * 128 * 4);
  float* pr2_wT = (float*)alloc(128 * 24 * 4);
  float* rg_wT  = (float*)alloc(128 * 24 * 4);
  if (off > ws_size) return;  // workspace too small (should not happen)

  prep_kernel<<<128, 256, 0, stream>>>(fp_w, q_w, k_w, v_w, o_w, s0_w, s1_w,
                                       fu_w, pr1_w, pr2_w, rg_w, fpw_bf, wcat_bf,
                                       o_wT, fu_wT, pr1_wT, s0_wT, s1_wT0, s1_wT1,
                                       pr2_wT, rg_wT);
  convfeatqkv_kernel<<<256, 512, 0, stream>>>(x, tc_w, tc_b, tc_bn_g, tc_bn_b,
                                              fpw_bf, fp_b, fp_ln_g, fp_ln_b,
                                              wcat_bf, q_b, k_b, v_b,
                                              q_bf, k_bf, vTp_bf);
  attn_kernel<<<1024, 512, 0, stream>>>(q_bf, k_bf, vTp_bf, adj, go);
  tail_kernel<<<256, 512, 0, stream>>>(go, x, o_wT, o_b, s0_wT, s0_b, s0_bn_g, s0_bn_b,
                                       s1_wT0, s1_wT1, s1_b, s1_bn_g, s1_bn_b, fusion_w,
                                       fu_wT, fu_b, fu_ln_g, fu_ln_b, pr1_wT, pr1_b,
                                       pr_ln_g, pr_ln_b, pr2_wT, pr2_b, rg_wT, rg_b, out);
}